// Round 7
// baseline (197.808 us; speedup 1.0000x reference)
//
#include <hip/hip_runtime.h>

typedef __attribute__((ext_vector_type(8))) _Float16 half8;
typedef __attribute__((ext_vector_type(4))) _Float16 half4;
typedef __attribute__((ext_vector_type(4))) float f32x4;
typedef __attribute__((ext_vector_type(16))) float f32x16;
typedef __attribute__((ext_vector_type(4))) int int4v;

#define BS 2
#define QLEN 2048
#define DIM 1024
#define NH 16
#define DPH 64
#define MTOT (BS * QLEN)   // 4096
#define LOG2E 1.44269504088896340736f

// ---------------------------------------------------------------------------
// fp32 -> fp16 conversion
// ---------------------------------------------------------------------------
__global__ void cvt_f32_f16(const float* __restrict__ src,
                            _Float16* __restrict__ dst, int n4) {
    int i = blockIdx.x * blockDim.x + threadIdx.x;
    int stride = gridDim.x * blockDim.x;
    for (int idx = i; idx < n4; idx += stride) {
        float4 v = ((const float4*)src)[idx];
        half4 o;
        o[0] = (_Float16)v.x; o[1] = (_Float16)v.y;
        o[2] = (_Float16)v.z; o[3] = (_Float16)v.w;
        ((half4*)dst)[idx] = o;
    }
}

__global__ void cvt_w4(const float* __restrict__ w0, const float* __restrict__ w1,
                       const float* __restrict__ w2, const float* __restrict__ w3,
                       _Float16* __restrict__ d0, _Float16* __restrict__ d1,
                       _Float16* __restrict__ d2, _Float16* __restrict__ d3) {
    const float* src = (blockIdx.y == 0) ? w0 : (blockIdx.y == 1) ? w1
                     : (blockIdx.y == 2) ? w2 : w3;
    _Float16* dst = (blockIdx.y == 0) ? d0 : (blockIdx.y == 1) ? d1
                  : (blockIdx.y == 2) ? d2 : d3;
    int idx = blockIdx.x * blockDim.x + threadIdx.x;   // 1024*256 = DIM*DIM/4
    float4 v = ((const float4*)src)[idx];
    half4 o;
    o[0] = (_Float16)v.x; o[1] = (_Float16)v.y;
    o[2] = (_Float16)v.z; o[3] = (_Float16)v.w;
    ((half4*)dst)[idx] = o;
}

// ---------------------------------------------------------------------------
__device__ __forceinline__ void gload_lds16(const _Float16* g, _Float16* l) {
    __builtin_amdgcn_global_load_lds(
        (const __attribute__((address_space(1))) void*)g,
        (__attribute__((address_space(3))) void*)l, 16, 0, 0);
}

// ---------------------------------------------------------------------------
// Fused QKV NT-GEMM. z=0: Q16 [b][h][t][d] scaled by (1/8)*log2e
//                    z=1: K16 [b][h][t][d], ZEROED where mask==0
//                    z=2: V16T [b][h][d][t]
// ---------------------------------------------------------------------------
__global__ __launch_bounds__(256) void gemm_qkv(
    const _Float16* __restrict__ A,
    const _Float16* __restrict__ Wq, const _Float16* __restrict__ Wk,
    const _Float16* __restrict__ Wv,
    const float* __restrict__ bq, const float* __restrict__ bk,
    const float* __restrict__ bv, const int* __restrict__ mask,
    _Float16* __restrict__ Qd, _Float16* __restrict__ Kd,
    _Float16* __restrict__ Vd) {
    const int K = 1024;
    __shared__ _Float16 sA[128 * 32];
    __shared__ _Float16 sB[128 * 32];
    const int z = blockIdx.z;
    const _Float16* W = (z == 0) ? Wq : (z == 1) ? Wk : Wv;
    const float* bias = (z == 0) ? bq : (z == 1) ? bk : bv;
    const int m0 = blockIdx.y * 128, n0 = blockIdx.x * 128;
    const int tid = threadIdx.x, w = tid >> 6, l = tid & 63;
    const int wr = (w >> 1) * 64, wc = (w & 1) * 64;
    const int r = l & 15, g = l >> 4;

    f32x4 acc[4][4] = {};

    for (int k0 = 0; k0 < K; k0 += 32) {
        __syncthreads();
#pragma unroll
        for (int i = 0; i < 2; ++i) {
            int c = tid + i * 256;
            int row = c >> 2, seg = (c & 3) * 8;
            gload_lds16(&A[(size_t)(m0 + row) * K + k0 + seg], &sA[c * 8]);
            gload_lds16(&W[(size_t)(n0 + row) * K + k0 + seg], &sB[c * 8]);
        }
        __syncthreads();

        half8 af[4], bf[4];
#pragma unroll
        for (int i = 0; i < 4; ++i) {
            af[i] = *(const half8*)&sA[(wr + i * 16 + r) * 32 + g * 8];
            bf[i] = *(const half8*)&sB[(wc + i * 16 + r) * 32 + g * 8];
        }
#pragma unroll
        for (int i = 0; i < 4; ++i)
#pragma unroll
            for (int j = 0; j < 4; ++j)
                acc[i][j] = __builtin_amdgcn_mfma_f32_16x16x32_f16(
                    af[i], bf[j], acc[i][j], 0, 0, 0);
    }

    float bv4[4];
#pragma unroll
    for (int j = 0; j < 4; ++j) bv4[j] = bias[n0 + wc + j * 16 + r];

#pragma unroll
    for (int i = 0; i < 4; ++i)
#pragma unroll
        for (int j = 0; j < 4; ++j) {
            const int n = n0 + wc + j * 16 + r;
            const int h = n >> 6, d = n & 63;
#pragma unroll
            for (int reg = 0; reg < 4; ++reg) {
                const int m = m0 + wr + i * 16 + g * 4 + reg;
                const int bb = m >> 11, tt = m & 2047;
                float v = acc[i][j][reg] + bv4[j];
                if (z == 0)
                    Qd[(((size_t)(bb * NH + h)) * QLEN + tt) * DPH + d] =
                        (_Float16)(v * (0.125f * LOG2E));
                else if (z == 1) {
                    // fold mask into K: zeroed row -> score 0 -> p = 1.0
                    v = mask[bb * QLEN + tt] ? v : 0.f;
                    Kd[(((size_t)(bb * NH + h)) * QLEN + tt) * DPH + d] = (_Float16)v;
                } else
                    Vd[(((size_t)(bb * NH + h)) * DPH + d) * QLEN + tt] = (_Float16)v;
            }
        }
}

// ---------------------------------------------------------------------------
// Output GEMM: out = CTX @ Wo^T + bo  (fp32 out)
// ---------------------------------------------------------------------------
__global__ __launch_bounds__(256) void gemm_out(
    const _Float16* __restrict__ A, const _Float16* __restrict__ W,
    const float* __restrict__ bias, float* __restrict__ out) {
    const int K = 1024;
    __shared__ _Float16 sA[128 * 32];
    __shared__ _Float16 sB[128 * 32];
    const int m0 = blockIdx.y * 128, n0 = blockIdx.x * 128;
    const int tid = threadIdx.x, w = tid >> 6, l = tid & 63;
    const int wr = (w >> 1) * 64, wc = (w & 1) * 64;
    const int r = l & 15, g = l >> 4;

    f32x4 acc[4][4] = {};

    for (int k0 = 0; k0 < K; k0 += 32) {
        __syncthreads();
#pragma unroll
        for (int i = 0; i < 2; ++i) {
            int c = tid + i * 256;
            int row = c >> 2, seg = (c & 3) * 8;
            gload_lds16(&A[(size_t)(m0 + row) * K + k0 + seg], &sA[c * 8]);
            gload_lds16(&W[(size_t)(n0 + row) * K + k0 + seg], &sB[c * 8]);
        }
        __syncthreads();

        half8 af[4], bf[4];
#pragma unroll
        for (int i = 0; i < 4; ++i) {
            af[i] = *(const half8*)&sA[(wr + i * 16 + r) * 32 + g * 8];
            bf[i] = *(const half8*)&sB[(wc + i * 16 + r) * 32 + g * 8];
        }
#pragma unroll
        for (int i = 0; i < 4; ++i)
#pragma unroll
            for (int j = 0; j < 4; ++j)
                acc[i][j] = __builtin_amdgcn_mfma_f32_16x16x32_f16(
                    af[i], bf[j], acc[i][j], 0, 0, 0);
    }

    float bv4[4];
#pragma unroll
    for (int j = 0; j < 4; ++j) bv4[j] = bias[n0 + wc + j * 16 + r];
#pragma unroll
    for (int i = 0; i < 4; ++i)
#pragma unroll
        for (int j = 0; j < 4; ++j) {
            const int n = n0 + wc + j * 16 + r;
#pragma unroll
            for (int reg = 0; reg < 4; ++reg) {
                const int m = m0 + wr + i * 16 + g * 4 + reg;
                out[(size_t)m * DIM + n] = acc[i][j][reg] + bv4[j];
            }
        }
}

// ---------------------------------------------------------------------------
// Flash attention, swapped-QK^T, in-register softmax, KEY-SPLIT x2.
// Block = 256 thr = 4 waves = 2 qsub x 2 ksplit; each wave 32q x 1024 keys.
// Grid = 32 qt x 32 bh = 1024 blocks; NO min-waves launch_bounds cap (R4/R5
// spill lesson): compiler allocates ~160 unified regs -> 3 blocks/CU resident
// = 12 waves/CU (vs R6's 8) and each wave's serial chain halves.
// Core = R6: permlane32_swap P-repack, s_setprio MFMA clusters, K-dbuf regs.
// Key-half-1 waves dump partial O^T + lsum to LDS; key-half-0 combines
// (combine logic correctness-proven in R4). Mask pre-folded into K.
// ---------------------------------------------------------------------------
__global__ __launch_bounds__(256) void attn_kernel(
    const _Float16* __restrict__ Qg, const _Float16* __restrict__ Kg,
    const _Float16* __restrict__ Vg, _Float16* __restrict__ ctx) {
    // XCD swizzle: all 32 blocks of a bh land on one XCD (flat%8 == bh%8)
    const int flat = blockIdx.x;               // 0..1023
    const int qt = (flat >> 3) & 31;           // 32 q-tiles of 64 rows
    const int bh = ((flat >> 8) << 3) | (flat & 7);
    const int b = bh >> 4, h = bh & 15;
    const _Float16* __restrict__ Qp = Qg + (size_t)bh * QLEN * DPH;
    const _Float16* __restrict__ Kp = Kg + (size_t)bh * QLEN * DPH;
    const _Float16* __restrict__ Vp = Vg + (size_t)bh * DPH * QLEN;

    const int tid = threadIdx.x, w = tid >> 6, l = tid & 63;
    const int qsub = w & 1, ksplit = w >> 1;
    const int ln = l & 31, hi = l >> 5;
    const int q0 = qt * 64 + qsub * 32;
    const int kbase = ksplit * 1024;           // this wave's 1024-key half

    __shared__ float sRed[2][64][33];          // partial O^T + lsum exchange

    // Q B-frags (4 k-steps over d=64), direct from global
    half8 qf[4];
#pragma unroll
    for (int ks = 0; ks < 4; ++ks)
        qf[ks] = *(const half8*)&Qp[(size_t)(q0 + ln) * DPH + ks * 16 + hi * 8];

    f32x16 accT[2] = {};
    float lsum = 0.f;

    auto loadK = [&](half8(&Kf)[2][4], int k0) {
#pragma unroll
        for (int kb = 0; kb < 2; ++kb)
#pragma unroll
            for (int ks = 0; ks < 4; ++ks)
                Kf[kb][ks] = *(const half8*)&Kp[(size_t)(kbase + k0 + kb * 32 + ln) * DPH +
                                                ks * 16 + hi * 8];
    };
    auto loadV = [&](half8(&Vf)[2][4], int k0) {
#pragma unroll
        for (int dblk = 0; dblk < 2; ++dblk)
#pragma unroll
            for (int ks = 0; ks < 4; ++ks)
                Vf[dblk][ks] = *(const half8*)&Vp[(size_t)(dblk * 32 + ln) * QLEN +
                                                  kbase + k0 + ks * 16 + hi * 8];
    };

    auto compute = [&](const half8(&Kf)[2][4], const half8(&Vf)[2][4]) {
#pragma unroll
        for (int kb = 0; kb < 2; ++kb) {
            // S^T tile (32 keys x 32 q)
            f32x16 st = {};
            __builtin_amdgcn_s_setprio(1);
#pragma unroll
            for (int ks = 0; ks < 4; ++ks)
                st = __builtin_amdgcn_mfma_f32_32x32x16_f16(
                    Kf[kb][ks], qf[ks], st, 0, 0, 0);
            __builtin_amdgcn_s_setprio(0);

            // p = 2^s (log2e folded into Q; masked K rows zero -> p = 1)
            int cpk[8];
#pragma unroll
            for (int i = 0; i < 8; ++i) {
                float e0 = __builtin_amdgcn_exp2f(st[2 * i]);
                float e1 = __builtin_amdgcn_exp2f(st[2 * i + 1]);
                lsum += e0 + e1;
                cpk[i] =
                    __builtin_bit_cast(int, __builtin_amdgcn_cvt_pkrtz(e0, e1));
            }
            // D-layout -> B-frag repack: one permlane32_swap per dword pair
            asm("v_permlane32_swap_b32 %0, %1" : "+v"(cpk[0]), "+v"(cpk[2]));
            asm("v_permlane32_swap_b32 %0, %1" : "+v"(cpk[1]), "+v"(cpk[3]));
            asm("v_permlane32_swap_b32 %0, %1" : "+v"(cpk[4]), "+v"(cpk[6]));
            asm("v_permlane32_swap_b32 %0, %1" : "+v"(cpk[5]), "+v"(cpk[7]));
            int4v b0 = {cpk[0], cpk[1], cpk[2], cpk[3]};
            int4v b1 = {cpk[4], cpk[5], cpk[6], cpk[7]};
            half8 Bf0 = __builtin_bit_cast(half8, b0);
            half8 Bf1 = __builtin_bit_cast(half8, b1);

            // O^T += V^T P^T for this kb
            __builtin_amdgcn_s_setprio(1);
#pragma unroll
            for (int dblk = 0; dblk < 2; ++dblk) {
                accT[dblk] = __builtin_amdgcn_mfma_f32_32x32x16_f16(
                    Vf[dblk][kb * 2 + 0], Bf0, accT[dblk], 0, 0, 0);
                accT[dblk] = __builtin_amdgcn_mfma_f32_32x32x16_f16(
                    Vf[dblk][kb * 2 + 1], Bf1, accT[dblk], 0, 0, 0);
            }
            __builtin_amdgcn_s_setprio(0);
        }
    };

    half8 Ka[2][4], Kb[2][4], Vf[2][4];
    loadK(Ka, 0);
    for (int t = 0; t < 16; t += 2) {          // 16 tiles of 64 keys per wave
        loadV(Vf, t * 64);
        loadK(Kb, (t + 1) * 64);
        compute(Ka, Vf);
        loadV(Vf, (t + 1) * 64);
        if (t + 2 < 16) loadK(Ka, (t + 2) * 64);
        compute(Kb, Vf);
    }

    // own-wave hi-half merge (keys split by hi within the wave)
    lsum += __shfl_xor(lsum, 32);

    // ---- cross-wave key-split combine via LDS (proven in R4) ----
    if (ksplit == 1) {
#pragma unroll
        for (int dblk = 0; dblk < 2; ++dblk)
#pragma unroll
            for (int i = 0; i < 16; ++i)
                sRed[qsub][l][dblk * 16 + i] = accT[dblk][i];
        sRed[qsub][l][32] = lsum;
    }
    __syncthreads();
    if (ksplit == 1) return;

#pragma unroll
    for (int dblk = 0; dblk < 2; ++dblk)
#pragma unroll
        for (int i = 0; i < 16; ++i)
            accT[dblk][i] += sRed[qsub][l][dblk * 16 + i];
    lsum += sRed[qsub][l][32];

    const float inv = 1.f / lsum;
    _Float16* cp = ctx + ((size_t)(b * QLEN) + q0 + ln) * DIM + h * DPH;
#pragma unroll
    for (int dblk = 0; dblk < 2; ++dblk)
#pragma unroll
        for (int j = 0; j < 4; ++j) {
            half4 o4;
#pragma unroll
            for (int e = 0; e < 4; ++e)
                o4[e] = (_Float16)(accT[dblk][4 * j + e] * inv);
            *(half4*)&cp[dblk * 32 + 8 * j + 4 * hi] = o4;
        }
}

// ---------------------------------------------------------------------------
extern "C" void kernel_launch(void* const* d_in, const int* in_sizes, int n_in,
                              void* d_out, int out_size, void* d_ws, size_t ws_size,
                              hipStream_t stream) {
    const float* x  = (const float*)d_in[0];
    const int* mask = (const int*)d_in[1];
    const float* Wq = (const float*)d_in[2];
    const float* bq = (const float*)d_in[3];
    const float* Wk = (const float*)d_in[4];
    const float* bk = (const float*)d_in[5];
    const float* Wv = (const float*)d_in[6];
    const float* bv = (const float*)d_in[7];
    const float* Wo = (const float*)d_in[8];
    const float* bo = (const float*)d_in[9];
    float* out = (float*)d_out;

    char* ws = (char*)d_ws;
    const size_t MB = 1u << 20;
    _Float16* X16  = (_Float16*)(ws + 0);
    _Float16* Wq16 = (_Float16*)(ws + 8 * MB);
    _Float16* Wk16 = (_Float16*)(ws + 10 * MB);
    _Float16* Wv16 = (_Float16*)(ws + 12 * MB);
    _Float16* Wo16 = (_Float16*)(ws + 14 * MB);
    _Float16* Q16  = (_Float16*)(ws + 16 * MB);  // [b][h][t][d], pre-scaled
    _Float16* K16  = (_Float16*)(ws + 24 * MB);  // [b][h][t][d], mask-zeroed
    _Float16* V16T = (_Float16*)(ws + 32 * MB);  // [b][h][d][t]
    _Float16* CTX  = (_Float16*)(ws + 40 * MB);  // [bt][dim]

    cvt_f32_f16<<<2048, 256, 0, stream>>>(x, X16, MTOT * DIM / 4);
    cvt_w4<<<dim3(1024, 4), 256, 0, stream>>>(Wq, Wk, Wv, Wo,
                                              Wq16, Wk16, Wv16, Wo16);

    gemm_qkv<<<dim3(8, 32, 3), 256, 0, stream>>>(
        X16, Wq16, Wk16, Wv16, bq, bk, bv, mask, Q16, K16, V16T);

    attn_kernel<<<1024, 256, 0, stream>>>(Q16, K16, V16T, CTX);

    gemm_out<<<dim3(8, 32), 256, 0, stream>>>(CTX, Wo16, bo, out);
}

// Round 8
// 142.171 us; speedup vs baseline: 1.3913x; 1.3913x over previous
//
#include <hip/hip_runtime.h>

typedef __attribute__((ext_vector_type(8))) _Float16 half8;
typedef __attribute__((ext_vector_type(4))) _Float16 half4;
typedef __attribute__((ext_vector_type(4))) float f32x4;
typedef __attribute__((ext_vector_type(16))) float f32x16;
typedef __attribute__((ext_vector_type(4))) int int4v;

#define BS 2
#define QLEN 2048
#define DIM 1024
#define NH 16
#define DPH 64
#define MTOT (BS * QLEN)   // 4096
#define LOG2E 1.44269504088896340736f

// ---------------------------------------------------------------------------
// fp32 -> fp16 conversion
// ---------------------------------------------------------------------------
__global__ void cvt_f32_f16(const float* __restrict__ src,
                            _Float16* __restrict__ dst, int n4) {
    int i = blockIdx.x * blockDim.x + threadIdx.x;
    int stride = gridDim.x * blockDim.x;
    for (int idx = i; idx < n4; idx += stride) {
        float4 v = ((const float4*)src)[idx];
        half4 o;
        o[0] = (_Float16)v.x; o[1] = (_Float16)v.y;
        o[2] = (_Float16)v.z; o[3] = (_Float16)v.w;
        ((half4*)dst)[idx] = o;
    }
}

__global__ void cvt_w4(const float* __restrict__ w0, const float* __restrict__ w1,
                       const float* __restrict__ w2, const float* __restrict__ w3,
                       _Float16* __restrict__ d0, _Float16* __restrict__ d1,
                       _Float16* __restrict__ d2, _Float16* __restrict__ d3) {
    const float* src = (blockIdx.y == 0) ? w0 : (blockIdx.y == 1) ? w1
                     : (blockIdx.y == 2) ? w2 : w3;
    _Float16* dst = (blockIdx.y == 0) ? d0 : (blockIdx.y == 1) ? d1
                  : (blockIdx.y == 2) ? d2 : d3;
    int idx = blockIdx.x * blockDim.x + threadIdx.x;   // 1024*256 = DIM*DIM/4
    float4 v = ((const float4*)src)[idx];
    half4 o;
    o[0] = (_Float16)v.x; o[1] = (_Float16)v.y;
    o[2] = (_Float16)v.z; o[3] = (_Float16)v.w;
    ((half4*)dst)[idx] = o;
}

// ---------------------------------------------------------------------------
__device__ __forceinline__ void gload_lds16(const _Float16* g, _Float16* l) {
    __builtin_amdgcn_global_load_lds(
        (const __attribute__((address_space(1))) void*)g,
        (__attribute__((address_space(3))) void*)l, 16, 0, 0);
}

// ---------------------------------------------------------------------------
// Fused QKV NT-GEMM. z=0: Q16 [b][h][t][d] scaled by (1/8)*log2e
//                    z=1: K16 [b][h][t][d], ZEROED where mask==0
//                    z=2: V16T [b][h][d][t]
// ---------------------------------------------------------------------------
__global__ __launch_bounds__(256) void gemm_qkv(
    const _Float16* __restrict__ A,
    const _Float16* __restrict__ Wq, const _Float16* __restrict__ Wk,
    const _Float16* __restrict__ Wv,
    const float* __restrict__ bq, const float* __restrict__ bk,
    const float* __restrict__ bv, const int* __restrict__ mask,
    _Float16* __restrict__ Qd, _Float16* __restrict__ Kd,
    _Float16* __restrict__ Vd) {
    const int K = 1024;
    __shared__ _Float16 sA[128 * 32];
    __shared__ _Float16 sB[128 * 32];
    const int z = blockIdx.z;
    const _Float16* W = (z == 0) ? Wq : (z == 1) ? Wk : Wv;
    const float* bias = (z == 0) ? bq : (z == 1) ? bk : bv;
    const int m0 = blockIdx.y * 128, n0 = blockIdx.x * 128;
    const int tid = threadIdx.x, w = tid >> 6, l = tid & 63;
    const int wr = (w >> 1) * 64, wc = (w & 1) * 64;
    const int r = l & 15, g = l >> 4;

    f32x4 acc[4][4] = {};

    for (int k0 = 0; k0 < K; k0 += 32) {
        __syncthreads();
#pragma unroll
        for (int i = 0; i < 2; ++i) {
            int c = tid + i * 256;
            int row = c >> 2, seg = (c & 3) * 8;
            gload_lds16(&A[(size_t)(m0 + row) * K + k0 + seg], &sA[c * 8]);
            gload_lds16(&W[(size_t)(n0 + row) * K + k0 + seg], &sB[c * 8]);
        }
        __syncthreads();

        half8 af[4], bf[4];
#pragma unroll
        for (int i = 0; i < 4; ++i) {
            af[i] = *(const half8*)&sA[(wr + i * 16 + r) * 32 + g * 8];
            bf[i] = *(const half8*)&sB[(wc + i * 16 + r) * 32 + g * 8];
        }
#pragma unroll
        for (int i = 0; i < 4; ++i)
#pragma unroll
            for (int j = 0; j < 4; ++j)
                acc[i][j] = __builtin_amdgcn_mfma_f32_16x16x32_f16(
                    af[i], bf[j], acc[i][j], 0, 0, 0);
    }

    float bv4[4];
#pragma unroll
    for (int j = 0; j < 4; ++j) bv4[j] = bias[n0 + wc + j * 16 + r];

#pragma unroll
    for (int i = 0; i < 4; ++i)
#pragma unroll
        for (int j = 0; j < 4; ++j) {
            const int n = n0 + wc + j * 16 + r;
            const int h = n >> 6, d = n & 63;
#pragma unroll
            for (int reg = 0; reg < 4; ++reg) {
                const int m = m0 + wr + i * 16 + g * 4 + reg;
                const int bb = m >> 11, tt = m & 2047;
                float v = acc[i][j][reg] + bv4[j];
                if (z == 0)
                    Qd[(((size_t)(bb * NH + h)) * QLEN + tt) * DPH + d] =
                        (_Float16)(v * (0.125f * LOG2E));
                else if (z == 1) {
                    // fold mask into K: zeroed row -> score 0 -> p = 1.0
                    v = mask[bb * QLEN + tt] ? v : 0.f;
                    Kd[(((size_t)(bb * NH + h)) * QLEN + tt) * DPH + d] = (_Float16)v;
                } else
                    Vd[(((size_t)(bb * NH + h)) * DPH + d) * QLEN + tt] = (_Float16)v;
            }
        }
}

// ---------------------------------------------------------------------------
// Output GEMM: out = CTX @ Wo^T + bo  (fp32 out)
// ---------------------------------------------------------------------------
__global__ __launch_bounds__(256) void gemm_out(
    const _Float16* __restrict__ A, const _Float16* __restrict__ W,
    const float* __restrict__ bias, float* __restrict__ out) {
    const int K = 1024;
    __shared__ _Float16 sA[128 * 32];
    __shared__ _Float16 sB[128 * 32];
    const int m0 = blockIdx.y * 128, n0 = blockIdx.x * 128;
    const int tid = threadIdx.x, w = tid >> 6, l = tid & 63;
    const int wr = (w >> 1) * 64, wc = (w & 1) * 64;
    const int r = l & 15, g = l >> 4;

    f32x4 acc[4][4] = {};

    for (int k0 = 0; k0 < K; k0 += 32) {
        __syncthreads();
#pragma unroll
        for (int i = 0; i < 2; ++i) {
            int c = tid + i * 256;
            int row = c >> 2, seg = (c & 3) * 8;
            gload_lds16(&A[(size_t)(m0 + row) * K + k0 + seg], &sA[c * 8]);
            gload_lds16(&W[(size_t)(n0 + row) * K + k0 + seg], &sB[c * 8]);
        }
        __syncthreads();

        half8 af[4], bf[4];
#pragma unroll
        for (int i = 0; i < 4; ++i) {
            af[i] = *(const half8*)&sA[(wr + i * 16 + r) * 32 + g * 8];
            bf[i] = *(const half8*)&sB[(wc + i * 16 + r) * 32 + g * 8];
        }
#pragma unroll
        for (int i = 0; i < 4; ++i)
#pragma unroll
            for (int j = 0; j < 4; ++j)
                acc[i][j] = __builtin_amdgcn_mfma_f32_16x16x32_f16(
                    af[i], bf[j], acc[i][j], 0, 0, 0);
    }

    float bv4[4];
#pragma unroll
    for (int j = 0; j < 4; ++j) bv4[j] = bias[n0 + wc + j * 16 + r];
#pragma unroll
    for (int i = 0; i < 4; ++i)
#pragma unroll
        for (int j = 0; j < 4; ++j) {
            const int n = n0 + wc + j * 16 + r;
#pragma unroll
            for (int reg = 0; reg < 4; ++reg) {
                const int m = m0 + wr + i * 16 + g * 4 + reg;
                out[(size_t)m * DIM + n] = acc[i][j][reg] + bv4[j];
            }
        }
}

// ---------------------------------------------------------------------------
// Flash attention v4: LDS-shared K/V + swapped-QK^T in-register softmax.
// Block = 512 thr = 8 waves = 4 qsub (32 q-rows each) x 2 ksplit (1024 keys).
// Grid = 16 qt x 32 bh = 512 blocks (2/CU target). Per 64-key step each
// ksplit half stages K [64][64] and V^T [64][64] into LDS ONCE via
// global_load_lds (4 issues/wave) -- 4x less vmem than per-wave reg loads
// (the R3/R6/R7 invariant bottleneck). Frags then come from LDS just-in-time
// (no 96-reg private K/V buffers -> ~110-125 unified regs -> 4 waves/SIMD).
// XOR swizzle (chunk ^= row&7) applied on BOTH sides (pre-swizzled global
// source + swizzled ds_read, rule #21) kills the 128B-stride 32-way conflict.
// Softmax core unchanged from R6 (fixed-max, permlane pack, mask in K).
// ---------------------------------------------------------------------------
__global__ __launch_bounds__(512) void attn_kernel(
    const _Float16* __restrict__ Qg, const _Float16* __restrict__ Kg,
    const _Float16* __restrict__ Vg, _Float16* __restrict__ ctx) {
    __shared__ __align__(16) char smem[65536];

    // XCD swizzle: all 16 blocks of a bh land on one XCD (flat%8 == bh%8)
    const int flat = blockIdx.x;               // 0..511
    const int qt = (flat >> 3) & 15;           // 16 q-tiles of 128 rows
    const int bh = ((flat >> 7) << 3) | (flat & 7);
    const int b = bh >> 4, h = bh & 15;
    const _Float16* __restrict__ Qp = Qg + (size_t)bh * QLEN * DPH;
    const _Float16* __restrict__ Kp = Kg + (size_t)bh * QLEN * DPH;
    const _Float16* __restrict__ Vp = Vg + (size_t)bh * DPH * QLEN;

    const int tid = threadIdx.x, w = tid >> 6, l = tid & 63;
    const int qsub = w & 3, ksplit = w >> 2;
    const int ln = l & 31, hi = l >> 5;
    const int q0 = qt * 128 + qsub * 32;
    const int kbase = ksplit * 1024;           // this half's 1024 keys

    // LDS regions (halves): K[ksplit][buf]: 64 keys x 64 d; V^T: 64 d x 64 keys
    _Float16* sK[2];
    _Float16* sV[2];
#pragma unroll
    for (int bb = 0; bb < 2; ++bb) {
        sK[bb] = (_Float16*)(smem + (ksplit * 2 + bb) * 8192);
        sV[bb] = (_Float16*)(smem + 32768 + (ksplit * 2 + bb) * 8192);
    }

    // Q B-frags (4 k-steps over d=64), direct from global
    half8 qf[4];
#pragma unroll
    for (int ks = 0; ks < 4; ++ks)
        qf[ks] = *(const half8*)&Qp[(size_t)(q0 + ln) * DPH + ks * 16 + hi * 8];

    f32x16 accT[2] = {};
    float lsum = 0.f;

    // stage 64-key tile tt of this half into buffer bb (4 gload_lds/wave).
    // Source chunk pre-swizzled: c = (l&7) ^ (l>>3) so LDS pos p holds chunk
    // p ^ (row&7); linear LDS dest (base + lane*16) per gload_lds semantics.
    auto stage = [&](int tt, int bb) {
        const int k0 = kbase + tt * 64;
        const int c8 = ((l & 7) ^ (l >> 3)) * 8;
        const int rl = l >> 3;
#pragma unroll
        for (int j = 0; j < 2; ++j) {
            const int r0 = qsub * 16 + j * 8;
            gload_lds16(&Kp[(size_t)(k0 + r0 + rl) * DPH + c8],
                        sK[bb] + r0 * 64 + l * 8);
            gload_lds16(&Vp[(size_t)(r0 + rl) * QLEN + k0 + c8],
                        sV[bb] + r0 * 64 + l * 8);
        }
    };

    auto compute = [&](int bb) {
        const _Float16* pK = sK[bb];
        const _Float16* pV = sV[bb];
#pragma unroll
        for (int kb = 0; kb < 2; ++kb) {
            // S^T tile (32 keys x 32 q); K-frag from LDS (swizzled pos)
            f32x16 st = {};
            __builtin_amdgcn_s_setprio(1);
#pragma unroll
            for (int ks = 0; ks < 4; ++ks) {
                const int pos = ((ks * 2 + hi) ^ (ln & 7)) * 8;
                half8 kf = *(const half8*)(pK + (kb * 32 + ln) * 64 + pos);
                st = __builtin_amdgcn_mfma_f32_32x32x16_f16(kf, qf[ks], st, 0, 0, 0);
            }
            __builtin_amdgcn_s_setprio(0);

            // p = 2^s (log2e folded into Q; masked K rows zero -> p = 1)
            int cpk[8];
#pragma unroll
            for (int i = 0; i < 8; ++i) {
                float e0 = __builtin_amdgcn_exp2f(st[2 * i]);
                float e1 = __builtin_amdgcn_exp2f(st[2 * i + 1]);
                lsum += e0 + e1;
                cpk[i] =
                    __builtin_bit_cast(int, __builtin_amdgcn_cvt_pkrtz(e0, e1));
            }
            // D-layout -> B-frag repack: one permlane32_swap per dword pair
            asm("v_permlane32_swap_b32 %0, %1" : "+v"(cpk[0]), "+v"(cpk[2]));
            asm("v_permlane32_swap_b32 %0, %1" : "+v"(cpk[1]), "+v"(cpk[3]));
            asm("v_permlane32_swap_b32 %0, %1" : "+v"(cpk[4]), "+v"(cpk[6]));
            asm("v_permlane32_swap_b32 %0, %1" : "+v"(cpk[5]), "+v"(cpk[7]));
            int4v b0 = {cpk[0], cpk[1], cpk[2], cpk[3]};
            int4v b1 = {cpk[4], cpk[5], cpk[6], cpk[7]};
            half8 Bf0 = __builtin_bit_cast(half8, b0);
            half8 Bf1 = __builtin_bit_cast(half8, b1);

            // O^T += V^T P^T; V-frag from LDS (swizzled pos)
            __builtin_amdgcn_s_setprio(1);
#pragma unroll
            for (int dblk = 0; dblk < 2; ++dblk) {
                const int j0 = ((kb * 4 + 0 + hi) ^ (ln & 7)) * 8;  // key-chunk kb*2+0
                const int j1 = ((kb * 4 + 2 + hi) ^ (ln & 7)) * 8;  // key-chunk kb*2+1
                half8 vf0 = *(const half8*)(pV + (dblk * 32 + ln) * 64 + j0);
                half8 vf1 = *(const half8*)(pV + (dblk * 32 + ln) * 64 + j1);
                accT[dblk] = __builtin_amdgcn_mfma_f32_32x32x16_f16(
                    vf0, Bf0, accT[dblk], 0, 0, 0);
                accT[dblk] = __builtin_amdgcn_mfma_f32_32x32x16_f16(
                    vf1, Bf1, accT[dblk], 0, 0, 0);
            }
            __builtin_amdgcn_s_setprio(0);
        }
    };

    // ---- main loop: 16 steps of 64 keys per half, LDS double-buffered ----
    stage(0, 0);
    __syncthreads();
    int buf = 0;
    for (int t = 0; t < 16; ++t) {
        stage((t + 1) & 15, buf ^ 1);    // t=15 wraps: redundant, uniform
        compute(buf);
        __syncthreads();
        buf ^= 1;
    }

    // own-wave hi-half merge (keys split by hi within the wave)
    lsum += __shfl_xor(lsum, 32);

    // ---- cross-wave key-split combine via LDS (aliased over staging) ----
    float* sRed = (float*)smem;                 // [4][64][33]
    if (ksplit == 1) {
        float* p = sRed + (qsub * 64 + l) * 33;
#pragma unroll
        for (int dblk = 0; dblk < 2; ++dblk)
#pragma unroll
            for (int i = 0; i < 16; ++i)
                p[dblk * 16 + i] = accT[dblk][i];
        p[32] = lsum;
    }
    __syncthreads();
    if (ksplit == 1) return;

    const float* p = sRed + (qsub * 64 + l) * 33;
#pragma unroll
    for (int dblk = 0; dblk < 2; ++dblk)
#pragma unroll
        for (int i = 0; i < 16; ++i)
            accT[dblk][i] += p[dblk * 16 + i];
    lsum += p[32];

    const float inv = 1.f / lsum;
    _Float16* cp = ctx + ((size_t)(b * QLEN) + q0 + ln) * DIM + h * DPH;
#pragma unroll
    for (int dblk = 0; dblk < 2; ++dblk)
#pragma unroll
        for (int j = 0; j < 4; ++j) {
            half4 o4;
#pragma unroll
            for (int e = 0; e < 4; ++e)
                o4[e] = (_Float16)(accT[dblk][4 * j + e] * inv);
            *(half4*)&cp[dblk * 32 + 8 * j + 4 * hi] = o4;
        }
}

// ---------------------------------------------------------------------------
extern "C" void kernel_launch(void* const* d_in, const int* in_sizes, int n_in,
                              void* d_out, int out_size, void* d_ws, size_t ws_size,
                              hipStream_t stream) {
    const float* x  = (const float*)d_in[0];
    const int* mask = (const int*)d_in[1];
    const float* Wq = (const float*)d_in[2];
    const float* bq = (const float*)d_in[3];
    const float* Wk = (const float*)d_in[4];
    const float* bk = (const float*)d_in[5];
    const float* Wv = (const float*)d_in[6];
    const float* bv = (const float*)d_in[7];
    const float* Wo = (const float*)d_in[8];
    const float* bo = (const float*)d_in[9];
    float* out = (float*)d_out;

    char* ws = (char*)d_ws;
    const size_t MB = 1u << 20;
    _Float16* X16  = (_Float16*)(ws + 0);
    _Float16* Wq16 = (_Float16*)(ws + 8 * MB);
    _Float16* Wk16 = (_Float16*)(ws + 10 * MB);
    _Float16* Wv16 = (_Float16*)(ws + 12 * MB);
    _Float16* Wo16 = (_Float16*)(ws + 14 * MB);
    _Float16* Q16  = (_Float16*)(ws + 16 * MB);  // [b][h][t][d], pre-scaled
    _Float16* K16  = (_Float16*)(ws + 24 * MB);  // [b][h][t][d], mask-zeroed
    _Float16* V16T = (_Float16*)(ws + 32 * MB);  // [b][h][d][t]
    _Float16* CTX  = (_Float16*)(ws + 40 * MB);  // [bt][dim]

    cvt_f32_f16<<<2048, 256, 0, stream>>>(x, X16, MTOT * DIM / 4);
    cvt_w4<<<dim3(1024, 4), 256, 0, stream>>>(Wq, Wk, Wv, Wo,
                                              Wq16, Wk16, Wv16, Wo16);

    gemm_qkv<<<dim3(8, 32, 3), 256, 0, stream>>>(
        X16, Wq16, Wk16, Wv16, bq, bk, bv, mask, Q16, K16, V16T);

    attn_kernel<<<512, 512, 0, stream>>>(Q16, K16, V16T, CTX);

    gemm_out<<<dim3(8, 32), 256, 0, stream>>>(CTX, Wo16, bo, out);
}